// Round 2
// baseline (561.144 us; speedup 1.0000x reference)
//
#include <hip/hip_runtime.h>
#include <hip/hip_bf16.h>

// B=8192 rows, N=64 nodes, C=256. Per node: MLP 1->C->C->1 on s=Q*Y,
// then softmax over [z0, z_1..z_64] per row. Output f32 [B, 65].
//
// Structure (round 2): block = (node, 2048-row chunk). W2[n] bf16 lives
// ENTIRELY in registers (per-wave 64-col slice = 32KB = 128 VGPR), loaded
// once. Loop over 16 batch tiles of 128 rows: compute H1 into LDS (VALU,
// interleaved with MFMA), 1 barrier/tile, double-buffered A.

#define BM 128
#define CHUNK 2048
#define NTILES (CHUNK / BM)

typedef __attribute__((ext_vector_type(8))) short bf16x8;
typedef __attribute__((ext_vector_type(4))) float f32x4;

__device__ __forceinline__ unsigned short f2bf(float f) {
    unsigned int u = __float_as_uint(f);
    u += 0x7FFFu + ((u >> 16) & 1u);   // RNE
    return (unsigned short)(u >> 16);
}

// ---------------------------------------------------------------------------
// Kernel 0: W2 [N][C][D] f32 -> W2t [N][D][C] bf16 (K-contiguous for MFMA B).
// ---------------------------------------------------------------------------
__global__ __launch_bounds__(256) void transpose_w2(
    const float* __restrict__ W2, unsigned short* __restrict__ W2t)
{
    __shared__ float tile[32][33];
    const int n  = blockIdx.z;
    const int c0 = blockIdx.y << 5;
    const int d0 = blockIdx.x << 5;
    const int tx = threadIdx.x & 31;
    const int ty = threadIdx.x >> 5;
    const float* src = W2 + ((size_t)n << 16);
    #pragma unroll
    for (int j = 0; j < 32; j += 8)
        tile[ty + j][tx] = src[(size_t)(c0 + ty + j) * 256 + d0 + tx];
    __syncthreads();
    unsigned short* dst = W2t + ((size_t)n << 16);
    #pragma unroll
    for (int j = 0; j < 32; j += 8)
        dst[(size_t)(d0 + ty + j) * 256 + c0 + tx] = f2bf(tile[tx][ty + j]);
}

// ---------------------------------------------------------------------------
// Kernel 1: W2-resident fused MLP GEMM.
// grid (4 chunks, 64 nodes), 512 threads = 8 waves in 2x4 (wr, wc).
// Wave owns 64x64 out sub-tile; B-frags breg[4][8] in regs for whole kernel.
// ---------------------------------------------------------------------------
__global__ __launch_bounds__(512, 2) void gemm_node(
    const float* __restrict__ Q, const float* __restrict__ Y,
    const float* __restrict__ W1, const float* __restrict__ b1,
    const unsigned short* __restrict__ W2t,
    const float* __restrict__ b2, const float* __restrict__ W3,
    const float* __restrict__ b3, float* __restrict__ Z)
{
    __shared__ short sA[2][BM * 256];     // 2 x 64KB, swizzled
    __shared__ float zpart[2][4][BM];     // 4KB

    const int tid  = threadIdx.x;
    const int lane = tid & 63;
    const int wave = tid >> 6;
    const int wr = wave >> 2;             // 0..1
    const int wc = wave & 3;              // 0..3
    const int n  = blockIdx.y;
    const int cr0 = blockIdx.x * CHUNK;

    const int srow = tid >> 2;            // 0..127  (staging row)
    const int skc  = (tid & 3) << 6;      // 0,64,128,192 (staging k base, shorts)

    const float* W1n = W1 + n * 256;
    const float* b1n = b1 + n * 256;
    const unsigned short* W2n = W2t + ((size_t)n << 16);

    // ---- B fragments: whole W2[n] wave-slice in registers (one-time) ----
    bf16x8 breg[4][8];
    #pragma unroll
    for (int p = 0; p < 4; p++) {
        #pragma unroll
        for (int ks = 0; ks < 8; ks++) {
            int col = (wc << 6) + (p << 4) + (lane & 15);
            int k   = (ks << 5) + ((lane >> 4) << 3);
            breg[p][ks] = *reinterpret_cast<const bf16x8*>(&W2n[(size_t)col * 256 + k]);
        }
    }

    // ---- s prefetch for tile 0 ----
    float qv, yv;
    {
        int gr = cr0 + srow;
        qv = Q[(size_t)gr * 64 + n];
        yv = Y[(size_t)gr * 64 + n];
    }

    // ---- prologue: stage tile 0 into buf 0 ----
    {
        const float sv = qv * yv;
        #pragma unroll
        for (int c = 0; c < 8; c++) {
            int k = skc + (c << 3);
            float4 w1a = *reinterpret_cast<const float4*>(&W1n[k]);
            float4 w1b = *reinterpret_cast<const float4*>(&W1n[k + 4]);
            float4 g1a = *reinterpret_cast<const float4*>(&b1n[k]);
            float4 g1b = *reinterpret_cast<const float4*>(&b1n[k + 4]);
            bf16x8 av;
            av[0] = f2bf(fmaxf(sv * w1a.x + g1a.x, 0.f));
            av[1] = f2bf(fmaxf(sv * w1a.y + g1a.y, 0.f));
            av[2] = f2bf(fmaxf(sv * w1a.z + g1a.z, 0.f));
            av[3] = f2bf(fmaxf(sv * w1a.w + g1a.w, 0.f));
            av[4] = f2bf(fmaxf(sv * w1b.x + g1b.x, 0.f));
            av[5] = f2bf(fmaxf(sv * w1b.y + g1b.y, 0.f));
            av[6] = f2bf(fmaxf(sv * w1b.z + g1b.z, 0.f));
            av[7] = f2bf(fmaxf(sv * w1b.w + g1b.w, 0.f));
            *reinterpret_cast<bf16x8*>(&sA[0][(srow * 256 + k) ^ ((srow & 15) << 3)]) = av;
        }
    }
    // ---- s prefetch for tile 1 ----
    {
        int gr = cr0 + BM + srow;
        qv = Q[(size_t)gr * 64 + n];
        yv = Y[(size_t)gr * 64 + n];
    }
    __syncthreads();

    for (int t = 0; t < NTILES; t++) {
        const int cur = t & 1;
        const float sv = qv * yv;   // s for tile (t+1) being staged this iter

        f32x4 acc[4][4] = {};

        // ---- interleaved: stage chunk (tile t+1 -> buf cur^1) + MFMA (buf cur) ----
        #pragma unroll
        for (int ks = 0; ks < 8; ks++) {
            {   // staging chunk ks (8 h1 values). t=15 wraps to tile 0: harmless.
                int k = skc + (ks << 3);
                float4 w1a = *reinterpret_cast<const float4*>(&W1n[k]);
                float4 w1b = *reinterpret_cast<const float4*>(&W1n[k + 4]);
                float4 g1a = *reinterpret_cast<const float4*>(&b1n[k]);
                float4 g1b = *reinterpret_cast<const float4*>(&b1n[k + 4]);
                bf16x8 av;
                av[0] = f2bf(fmaxf(sv * w1a.x + g1a.x, 0.f));
                av[1] = f2bf(fmaxf(sv * w1a.y + g1a.y, 0.f));
                av[2] = f2bf(fmaxf(sv * w1a.z + g1a.z, 0.f));
                av[3] = f2bf(fmaxf(sv * w1a.w + g1a.w, 0.f));
                av[4] = f2bf(fmaxf(sv * w1b.x + g1b.x, 0.f));
                av[5] = f2bf(fmaxf(sv * w1b.y + g1b.y, 0.f));
                av[6] = f2bf(fmaxf(sv * w1b.z + g1b.z, 0.f));
                av[7] = f2bf(fmaxf(sv * w1b.w + g1b.w, 0.f));
                *reinterpret_cast<bf16x8*>(&sA[cur ^ 1][(srow * 256 + k) ^ ((srow & 15) << 3)]) = av;
            }
            // MFMA on tile t from buf[cur]
            bf16x8 afr[4];
            #pragma unroll
            for (int m = 0; m < 4; m++) {
                int row = (wr << 6) + (m << 4) + (lane & 15);
                int k   = (ks << 5) + ((lane >> 4) << 3);
                afr[m] = *reinterpret_cast<const bf16x8*>(&sA[cur][(row * 256 + k) ^ ((row & 15) << 3)]);
            }
            #pragma unroll
            for (int m = 0; m < 4; m++)
                #pragma unroll
                for (int p = 0; p < 4; p++)
                    acc[m][p] = __builtin_amdgcn_mfma_f32_16x16x32_bf16(afr[m], breg[p][ks], acc[m][p], 0, 0, 0);
        }

        // ---- s prefetch for tile t+2 (wraps harmlessly) ----
        {
            int gr = cr0 + (((t + 2) & 15) * BM) + srow;
            qv = Q[(size_t)gr * 64 + n];
            yv = Y[(size_t)gr * 64 + n];
        }

        // ---- epilogue: z_partial = sum_d relu(acc + b2[d]) * W3[d] ----
        #pragma unroll
        for (int m = 0; m < 4; m++) {
            #pragma unroll
            for (int j = 0; j < 4; j++) {
                float pz = 0.f;
                #pragma unroll
                for (int p = 0; p < 4; p++) {
                    int d = (wc << 6) + (p << 4) + (lane & 15);
                    pz += fmaxf(acc[m][p][j] + b2[n * 256 + d], 0.f) * W3[n * 256 + d];
                }
                pz += __shfl_xor(pz, 1, 64);
                pz += __shfl_xor(pz, 2, 64);
                pz += __shfl_xor(pz, 4, 64);
                pz += __shfl_xor(pz, 8, 64);
                if ((lane & 15) == 0) {
                    int row = (wr << 6) + (m << 4) + ((lane >> 4) << 2) + j;
                    zpart[cur][wc][row] = pz;
                }
            }
        }
        __syncthreads();
        if (tid < BM) {
            float z = zpart[cur][0][tid] + zpart[cur][1][tid]
                    + zpart[cur][2][tid] + zpart[cur][3][tid] + b3[n];
            Z[(size_t)(cr0 + t * BM + tid) * 64 + n] = z;
        }
    }
}

// ---------------------------------------------------------------------------
// Kernel 2: per-row 65-way softmax. One wave per batch row.
// ---------------------------------------------------------------------------
__global__ __launch_bounds__(256) void softmax_rows(
    const float* __restrict__ Q, const float* __restrict__ Y,
    const float* __restrict__ Z, const float* __restrict__ bias0,
    float* __restrict__ out)
{
    const int lane = threadIdx.x & 63;
    const int wv   = threadIdx.x >> 6;
    const int b    = (blockIdx.x << 2) + wv;

    float s = Q[(size_t)b * 64 + lane] * Y[(size_t)b * 64 + lane];
    float ssum = s;
    #pragma unroll
    for (int mask = 32; mask >= 1; mask >>= 1) ssum += __shfl_xor(ssum, mask, 64);
    const float z0 = bias0[0] - ssum;

    float zl = Z[(size_t)b * 64 + lane];
    float mx = zl;
    #pragma unroll
    for (int mask = 32; mask >= 1; mask >>= 1) mx = fmaxf(mx, __shfl_xor(mx, mask, 64));
    mx = fmaxf(mx, z0);

    float el = expf(zl - mx);
    float e0 = expf(z0 - mx);
    float den = el;
    #pragma unroll
    for (int mask = 32; mask >= 1; mask >>= 1) den += __shfl_xor(den, mask, 64);
    den += e0;
    const float inv = 1.0f / den;

    out[(size_t)b * 65 + 1 + lane] = el * inv;
    if (lane == 0) out[(size_t)b * 65] = e0 * inv;
}

// ---------------------------------------------------------------------------
extern "C" void kernel_launch(void* const* d_in, const int* in_sizes, int n_in,
                              void* d_out, int out_size, void* d_ws, size_t ws_size,
                              hipStream_t stream)
{
    const float* Q     = (const float*)d_in[0];
    const float* Y     = (const float*)d_in[1];
    const float* W1    = (const float*)d_in[2];
    const float* b1    = (const float*)d_in[3];
    const float* W2    = (const float*)d_in[4];
    const float* b2    = (const float*)d_in[5];
    const float* W3    = (const float*)d_in[6];
    const float* b3    = (const float*)d_in[7];
    const float* bias0 = (const float*)d_in[8];
    float* out = (float*)d_out;

    // workspace: W2t bf16 (8.39 MB) | Z f32 logits (2.10 MB)
    unsigned short* W2t = (unsigned short*)d_ws;
    float* Z = (float*)((char*)d_ws + (size_t)64 * 256 * 256 * 2);

    transpose_w2<<<dim3(8, 8, 64), 256, 0, stream>>>(W2, W2t);
    gemm_node<<<dim3(4, 64), 512, 0, stream>>>(Q, Y, W1, b1, W2t, b2, W3, b3, Z);
    softmax_rows<<<2048, 256, 0, stream>>>(Q, Y, Z, bias0, out);
}

// Round 3
// 148.713 us; speedup vs baseline: 3.7733x; 3.7733x over previous
//
#include <hip/hip_runtime.h>
#include <hip/hip_bf16.h>

// B=8192 rows, N=64 nodes, C=256. Per node: MLP 1->C->C->1 on s=Q*Y,
// then softmax over [z0, z_1..z_64] per row. Output f32 [B, 65].
//
// Round 3: W2[n] resident in registers, spill-proofed.
//  - 8 waves x (32 cols each): breg[2][8] = 64 VGPR/wave (was 128 -> spilled)
//  - staging: thread owns fixed 8-short k-window, 8 rows -> hoisted W1/b1 = 16 regs
//  - A-tile LDS: 4 K-panels of [128][64] shorts (+8 pad/panel), XOR swizzle
//    ^((row&7)<<3): read AND write conflict-free (hand-verified bank quads)
//  - 1 barrier/tile, double-buffered A, s-values double-prefetched

#define BM 128
#define CHUNK 2048
#define NTILES (CHUNK / BM)
#define PANEL 8200   // (128*64 + 8) shorts per panel; pad keeps quads distinct

typedef __attribute__((ext_vector_type(8))) short bf16x8;
typedef __attribute__((ext_vector_type(4))) float f32x4;

__device__ __forceinline__ unsigned short f2bf(float f) {
    unsigned int u = __float_as_uint(f);
    u += 0x7FFFu + ((u >> 16) & 1u);   // RNE
    return (unsigned short)(u >> 16);
}

__device__ __forceinline__ short f2bf_s(float f) {
    __hip_bfloat16 h = __float2bfloat16(f);
    return *reinterpret_cast<short*>(&h);
}

// ---------------------------------------------------------------------------
// Kernel 0: W2 [N][C][D] f32 -> W2t [N][D][C] bf16 (K-contiguous for MFMA B).
// ---------------------------------------------------------------------------
__global__ __launch_bounds__(256) void transpose_w2(
    const float* __restrict__ W2, unsigned short* __restrict__ W2t)
{
    __shared__ float tile[32][33];
    const int n  = blockIdx.z;
    const int c0 = blockIdx.y << 5;
    const int d0 = blockIdx.x << 5;
    const int tx = threadIdx.x & 31;
    const int ty = threadIdx.x >> 5;
    const float* src = W2 + ((size_t)n << 16);
    #pragma unroll
    for (int j = 0; j < 32; j += 8)
        tile[ty + j][tx] = src[(size_t)(c0 + ty + j) * 256 + d0 + tx];
    __syncthreads();
    unsigned short* dst = W2t + ((size_t)n << 16);
    #pragma unroll
    for (int j = 0; j < 32; j += 8)
        dst[(size_t)(d0 + ty + j) * 256 + c0 + tx] = f2bf(tile[tx][ty + j]);
}

// ---------------------------------------------------------------------------
// Kernel 1: W2-resident fused MLP GEMM. grid (4 chunks, 64 nodes), 512 thr.
// ---------------------------------------------------------------------------
__global__ __launch_bounds__(512, 1) void gemm_node(
    const float* __restrict__ Q, const float* __restrict__ Y,
    const float* __restrict__ W1, const float* __restrict__ b1,
    const unsigned short* __restrict__ W2t,
    const float* __restrict__ b2, const float* __restrict__ W3,
    const float* __restrict__ b3, float* __restrict__ Z)
{
    __shared__ short sA[2][4 * PANEL];    // 2 x 65.6KB
    __shared__ float zpart[2][8][BM];     // 8KB

    const int tid  = threadIdx.x;
    const int lane = tid & 63;
    const int wave = tid >> 6;            // 0..7 : col block of 32
    const int n    = blockIdx.y;
    const int cr0  = blockIdx.x * CHUNK;

    // staging assignment: fixed k-window, 8 rows (r0 + 16j)
    const int r0  = tid >> 5;             // 0..15
    const int kc  = (tid & 31) << 3;      // short index 0..248
    const int pan = kc >> 6;              // 0..3
    const int k64 = kc & 63;

    const float* W1n = W1 + n * 256;
    const float* b1n = b1 + n * 256;
    const unsigned short* W2n = W2t + ((size_t)n << 16);

    // ---- hoisted per-thread W1/b1 window (16 regs) ----
    float pw1[8], pb1[8];
    {
        float4 wa = *reinterpret_cast<const float4*>(&W1n[kc]);
        float4 wb = *reinterpret_cast<const float4*>(&W1n[kc + 4]);
        float4 ba = *reinterpret_cast<const float4*>(&b1n[kc]);
        float4 bb = *reinterpret_cast<const float4*>(&b1n[kc + 4]);
        pw1[0]=wa.x; pw1[1]=wa.y; pw1[2]=wa.z; pw1[3]=wa.w;
        pw1[4]=wb.x; pw1[5]=wb.y; pw1[6]=wb.z; pw1[7]=wb.w;
        pb1[0]=ba.x; pb1[1]=ba.y; pb1[2]=ba.z; pb1[3]=ba.w;
        pb1[4]=bb.x; pb1[5]=bb.y; pb1[6]=bb.z; pb1[7]=bb.w;
    }

    // ---- B fragments: wave's 32-col slice of W2[n] in regs (64 VGPR) ----
    bf16x8 breg[2][8];
    #pragma unroll
    for (int p = 0; p < 2; p++)
        #pragma unroll
        for (int ks = 0; ks < 8; ks++) {
            int col = (wave << 5) + (p << 4) + (lane & 15);
            int k   = (ks << 5) + ((lane >> 4) << 3);
            breg[p][ks] = *reinterpret_cast<const bf16x8*>(&W2n[(size_t)col * 256 + k]);
        }

    // ---- hoisted epilogue constants ----
    float w3v[2], b2v[2];
    #pragma unroll
    for (int p = 0; p < 2; p++) {
        int d = (wave << 5) + (p << 4) + (lane & 15);
        w3v[p] = W3[n * 256 + d];
        b2v[p] = b2[n * 256 + d];
    }
    const float b3n = b3[n];

    // ---- s prefetch (tile 0 -> sE), stage tile 0 -> buf 0 ----
    float sE[8], sO[8];
    #pragma unroll
    for (int j = 0; j < 8; j++) {
        int gr = cr0 + r0 + (j << 4);
        sE[j] = Q[(size_t)gr * 64 + n] * Y[(size_t)gr * 64 + n];
    }
    #pragma unroll
    for (int j = 0; j < 8; j++) {
        const float sv = sE[j];
        bf16x8 av;
        #pragma unroll
        for (int i = 0; i < 8; i++)
            av[i] = f2bf_s(fmaxf(fmaf(sv, pw1[i], pb1[i]), 0.f));
        int rj = r0 + (j << 4);
        *reinterpret_cast<bf16x8*>(
            &sA[0][pan * PANEL + (((rj << 6) + k64) ^ ((rj & 7) << 3))]) = av;
    }
    #pragma unroll
    for (int j = 0; j < 8; j++) {
        int gr = cr0 + BM + r0 + (j << 4);
        sO[j] = Q[(size_t)gr * 64 + n] * Y[(size_t)gr * 64 + n];
    }
    __syncthreads();

    // ---- main loop: iter T computes tile T (buf T&1), stages tile T+1 ----
#define TILE_ITER(T, CUR, SST, SPF)                                            \
    do {                                                                       \
        f32x4 acc[8][2] = {};                                                  \
        _Pragma("unroll")                                                      \
        for (int ks = 0; ks < 8; ks++) {                                       \
            { /* stage chunk: row r0+16*ks of tile T+1 into buf CUR^1 */       \
                const float sv = SST[ks];                                      \
                bf16x8 av;                                                     \
                _Pragma("unroll")                                              \
                for (int i = 0; i < 8; i++)                                    \
                    av[i] = f2bf_s(fmaxf(fmaf(sv, pw1[i], pb1[i]), 0.f));      \
                int rj = r0 + (ks << 4);                                       \
                *reinterpret_cast<bf16x8*>(                                    \
                    &sA[(CUR) ^ 1][pan * PANEL +                               \
                        (((rj << 6) + k64) ^ ((rj & 7) << 3))]) = av;          \
            }                                                                  \
            bf16x8 afr[8];                                                     \
            const int rpan = ks >> 1;                                          \
            const int rk   = ((ks & 1) << 5) + ((lane >> 4) << 3);             \
            _Pragma("unroll")                                                  \
            for (int m = 0; m < 8; m++) {                                      \
                int row = (m << 4) + (lane & 15);                              \
                afr[m] = *reinterpret_cast<const bf16x8*>(                     \
                    &sA[CUR][rpan * PANEL +                                    \
                        (((row << 6) + rk) ^ ((row & 7) << 3))]);              \
            }                                                                  \
            _Pragma("unroll")                                                  \
            for (int m = 0; m < 8; m++)                                        \
                _Pragma("unroll")                                              \
                for (int p = 0; p < 2; p++)                                    \
                    acc[m][p] = __builtin_amdgcn_mfma_f32_16x16x32_bf16(       \
                        afr[m], breg[p][ks], acc[m][p], 0, 0, 0);              \
        }                                                                      \
        _Pragma("unroll")                                                      \
        for (int j = 0; j < 8; j++) { /* prefetch s(T+2) */                    \
            int gr = cr0 + ((((T) + 2) & 15) << 7) + r0 + (j << 4);            \
            SPF[j] = Q[(size_t)gr * 64 + n] * Y[(size_t)gr * 64 + n];          \
        }                                                                      \
        _Pragma("unroll")                                                      \
        for (int m = 0; m < 8; m++) {                                          \
            _Pragma("unroll")                                                  \
            for (int j = 0; j < 4; j++) {                                      \
                float pz = fmaxf(acc[m][0][j] + b2v[0], 0.f) * w3v[0]          \
                         + fmaxf(acc[m][1][j] + b2v[1], 0.f) * w3v[1];         \
                pz += __shfl_xor(pz, 1, 64);                                   \
                pz += __shfl_xor(pz, 2, 64);                                   \
                pz += __shfl_xor(pz, 4, 64);                                   \
                pz += __shfl_xor(pz, 8, 64);                                   \
                if ((lane & 15) == 0)                                          \
                    zpart[CUR][wave][(m << 4) + ((lane >> 4) << 2) + j] = pz;  \
            }                                                                  \
        }                                                                      \
        __syncthreads();                                                       \
        if (tid < BM) {                                                        \
            float z = zpart[CUR][0][tid] + zpart[CUR][1][tid]                  \
                    + zpart[CUR][2][tid] + zpart[CUR][3][tid]                  \
                    + zpart[CUR][4][tid] + zpart[CUR][5][tid]                  \
                    + zpart[CUR][6][tid] + zpart[CUR][7][tid] + b3n;           \
            Z[(size_t)(cr0 + ((T) << 7) + tid) * 64 + n] = z;                  \
        }                                                                      \
    } while (0)

    for (int tt = 0; tt < NTILES; tt += 2) {
        TILE_ITER(tt, 0, sO, sE);
        TILE_ITER(tt + 1, 1, sE, sO);
    }
#undef TILE_ITER
}

// ---------------------------------------------------------------------------
// Kernel 2: per-row 65-way softmax. One wave per batch row.
// ---------------------------------------------------------------------------
__global__ __launch_bounds__(256) void softmax_rows(
    const float* __restrict__ Q, const float* __restrict__ Y,
    const float* __restrict__ Z, const float* __restrict__ bias0,
    float* __restrict__ out)
{
    const int lane = threadIdx.x & 63;
    const int wv   = threadIdx.x >> 6;
    const int b    = (blockIdx.x << 2) + wv;

    float s = Q[(size_t)b * 64 + lane] * Y[(size_t)b * 64 + lane];
    float ssum = s;
    #pragma unroll
    for (int mask = 32; mask >= 1; mask >>= 1) ssum += __shfl_xor(ssum, mask, 64);
    const float z0 = bias0[0] - ssum;

    float zl = Z[(size_t)b * 64 + lane];
    float mx = zl;
    #pragma unroll
    for (int mask = 32; mask >= 1; mask >>= 1) mx = fmaxf(mx, __shfl_xor(mx, mask, 64));
    mx = fmaxf(mx, z0);

    float el = expf(zl - mx);
    float e0 = expf(z0 - mx);
    float den = el;
    #pragma unroll
    for (int mask = 32; mask >= 1; mask >>= 1) den += __shfl_xor(den, mask, 64);
    den += e0;
    const float inv = 1.0f / den;

    out[(size_t)b * 65 + 1 + lane] = el * inv;
    if (lane == 0) out[(size_t)b * 65] = e0 * inv;
}

// ---------------------------------------------------------------------------
extern "C" void kernel_launch(void* const* d_in, const int* in_sizes, int n_in,
                              void* d_out, int out_size, void* d_ws, size_t ws_size,
                              hipStream_t stream)
{
    const float* Q     = (const float*)d_in[0];
    const float* Y     = (const float*)d_in[1];
    const float* W1    = (const float*)d_in[2];
    const float* b1    = (const float*)d_in[3];
    const float* W2    = (const float*)d_in[4];
    const float* b2    = (const float*)d_in[5];
    const float* W3    = (const float*)d_in[6];
    const float* b3    = (const float*)d_in[7];
    const float* bias0 = (const float*)d_in[8];
    float* out = (float*)d_out;

    // workspace: W2t bf16 (8.39 MB) | Z f32 logits (2.10 MB)
    unsigned short* W2t = (unsigned short*)d_ws;
    float* Z = (float*)((char*)d_ws + (size_t)64 * 256 * 256 * 2);

    transpose_w2<<<dim3(8, 8, 64), 256, 0, stream>>>(W2, W2t);
    gemm_node<<<dim3(4, 64), 512, 0, stream>>>(Q, Y, W1, b1, W2t, b2, W3, b3, Z);
    softmax_rows<<<2048, 256, 0, stream>>>(Q, Y, Z, bias0, out);
}

// Round 4
// 97.036 us; speedup vs baseline: 5.7828x; 1.5326x over previous
//
#include <hip/hip_runtime.h>
#include <hip/hip_bf16.h>

// B=8192 rows, N=64 nodes, C=256. Per node: MLP 1->C->C->1 on s=Q*Y,
// then softmax over [z0, z_1..z_64] per row. Output f32 [B, 65].
//
// Round 4: W2[n]-in-registers GEMM, de-stalled.
//  - DPP (VALU-pipe) 16-lane epilogue reduction, no shfl/ds_bpermute
//  - cheap RNE bf16 pair-pack (inputs relu'd, no NaN path)
//  - Q/Y prefetch at loop top (2 tiles ahead), runtime-cur single body
//  - s_setprio around MFMA clusters; Z stored node-major (coalesced)

#define BM 128
#define CHUNK 2048
#define NTILES (CHUNK / BM)
#define PANEL 8200   // (128*64 + 8) shorts per K-panel (conflict-free, measured)

typedef __attribute__((ext_vector_type(8))) short bf16x8;
typedef __attribute__((ext_vector_type(4))) float f32x4;

__device__ __forceinline__ unsigned short f2bf(float f) {
    unsigned int u = __float_as_uint(f);
    u += 0x7FFFu + ((u >> 16) & 1u);   // RNE
    return (unsigned short)(u >> 16);
}

// pack two f32 -> u32 of 2 bf16 (RNE). Inputs are post-relu (>=0): no NaN/ovf.
__device__ __forceinline__ unsigned int pack2bf(float a, float b) {
    unsigned int ua = __float_as_uint(a), ub = __float_as_uint(b);
    ua += 0x7FFFu + ((ua >> 16) & 1u);
    ub += 0x7FFFu + ((ub >> 16) & 1u);
    return (ua >> 16) | (ub & 0xFFFF0000u);
}

// sum across the 16 lanes of each DPP row; every lane ends with the row total
__device__ __forceinline__ float row_reduce16(float x) {
    int v;
    v = __builtin_amdgcn_update_dpp(0, __float_as_int(x), 0xB1, 0xF, 0xF, false);  // quad_perm [1,0,3,2]
    x += __int_as_float(v);
    v = __builtin_amdgcn_update_dpp(0, __float_as_int(x), 0x4E, 0xF, 0xF, false);  // quad_perm [2,3,0,1]
    x += __int_as_float(v);
    v = __builtin_amdgcn_update_dpp(0, __float_as_int(x), 0x124, 0xF, 0xF, false); // row_ror:4
    x += __int_as_float(v);
    v = __builtin_amdgcn_update_dpp(0, __float_as_int(x), 0x128, 0xF, 0xF, false); // row_ror:8
    x += __int_as_float(v);
    return x;
}

// ---------------------------------------------------------------------------
// Kernel 0: W2 [N][C][D] f32 -> W2t [N][D][C] bf16 (K-contiguous for MFMA B).
// ---------------------------------------------------------------------------
__global__ __launch_bounds__(256) void transpose_w2(
    const float* __restrict__ W2, unsigned short* __restrict__ W2t)
{
    __shared__ float tile[32][33];
    const int n  = blockIdx.z;
    const int c0 = blockIdx.y << 5;
    const int d0 = blockIdx.x << 5;
    const int tx = threadIdx.x & 31;
    const int ty = threadIdx.x >> 5;
    const float* src = W2 + ((size_t)n << 16);
    #pragma unroll
    for (int j = 0; j < 32; j += 8)
        tile[ty + j][tx] = src[(size_t)(c0 + ty + j) * 256 + d0 + tx];
    __syncthreads();
    unsigned short* dst = W2t + ((size_t)n << 16);
    #pragma unroll
    for (int j = 0; j < 32; j += 8)
        dst[(size_t)(d0 + ty + j) * 256 + c0 + tx] = f2bf(tile[tx][ty + j]);
}

// ---------------------------------------------------------------------------
// Kernel 1: W2-resident fused MLP GEMM. grid (4 chunks, 64 nodes), 512 thr.
// ---------------------------------------------------------------------------
__global__ __launch_bounds__(512, 1) void gemm_node(
    const float* __restrict__ Q, const float* __restrict__ Y,
    const float* __restrict__ W1, const float* __restrict__ b1,
    const unsigned short* __restrict__ W2t,
    const float* __restrict__ b2, const float* __restrict__ W3,
    const float* __restrict__ b3, float* __restrict__ Z)
{
    __shared__ short sA[2][4 * PANEL];    // 2 x 65.6KB, double-buffered A
    __shared__ float zpart[2][BM][10];    // [buf][row][wave(+pad)] 10.2KB

    const int tid  = threadIdx.x;
    const int lane = tid & 63;
    const int wave = tid >> 6;            // 0..7 : col block of 32
    const int n    = blockIdx.y;
    const int cr0  = blockIdx.x * CHUNK;

    // staging assignment: fixed 8-short k-window, rows r0 + 16j
    const int r0  = tid >> 5;             // 0..15
    const int kc  = (tid & 31) << 3;      // short index 0..248
    const int pan = kc >> 6;              // 0..3
    const int k64 = kc & 63;

    const float* W1n = W1 + n * 256;
    const float* b1n = b1 + n * 256;
    const unsigned short* W2n = W2t + ((size_t)n << 16);
    float* Zn = Z + ((size_t)n << 13);    // node-major Z [64][8192]

    // ---- hoisted per-thread W1/b1 window (16 regs) ----
    float pw1[8], pb1[8];
    {
        float4 wa = *reinterpret_cast<const float4*>(&W1n[kc]);
        float4 wb = *reinterpret_cast<const float4*>(&W1n[kc + 4]);
        float4 ba = *reinterpret_cast<const float4*>(&b1n[kc]);
        float4 bb = *reinterpret_cast<const float4*>(&b1n[kc + 4]);
        pw1[0]=wa.x; pw1[1]=wa.y; pw1[2]=wa.z; pw1[3]=wa.w;
        pw1[4]=wb.x; pw1[5]=wb.y; pw1[6]=wb.z; pw1[7]=wb.w;
        pb1[0]=ba.x; pb1[1]=ba.y; pb1[2]=ba.z; pb1[3]=ba.w;
        pb1[4]=bb.x; pb1[5]=bb.y; pb1[6]=bb.z; pb1[7]=bb.w;
    }

    // ---- B fragments: wave's 32-col slice of W2[n] in regs (64 VGPR) ----
    bf16x8 breg[2][8];
    #pragma unroll
    for (int p = 0; p < 2; p++)
        #pragma unroll
        for (int ks = 0; ks < 8; ks++) {
            int col = (wave << 5) + (p << 4) + (lane & 15);
            int k   = (ks << 5) + ((lane >> 4) << 3);
            breg[p][ks] = *reinterpret_cast<const bf16x8*>(&W2n[(size_t)col * 256 + k]);
        }

    // ---- hoisted epilogue constants ----
    float w3v[2], b2v[2];
    #pragma unroll
    for (int p = 0; p < 2; p++) {
        int d = (wave << 5) + (p << 4) + (lane & 15);
        w3v[p] = W3[n * 256 + d];
        b2v[p] = b2[n * 256 + d];
    }
    const float b3n = b3[n];

    // ---- staging helper data flow:
    // qv/yv hold raw Q,Y for the NEXT tile to stage; sStage = their product.
    float qv[8], yv[8];
    #pragma unroll
    for (int j = 0; j < 8; j++) {
        int gr = cr0 + r0 + (j << 4);
        qv[j] = Q[(size_t)gr * 64 + n];
        yv[j] = Y[(size_t)gr * 64 + n];
    }
    // stage tile 0 into buf 0
    #pragma unroll
    for (int j = 0; j < 8; j++) {
        const float sv = qv[j] * yv[j];
        uint4 wv;
        float h[8];
        #pragma unroll
        for (int i = 0; i < 8; i++)
            h[i] = fmaxf(fmaf(sv, pw1[i], pb1[i]), 0.f);
        wv.x = pack2bf(h[0], h[1]); wv.y = pack2bf(h[2], h[3]);
        wv.z = pack2bf(h[4], h[5]); wv.w = pack2bf(h[6], h[7]);
        int rj = r0 + (j << 4);
        *reinterpret_cast<uint4*>(
            &sA[0][pan * PANEL + (((rj << 6) + k64) ^ ((rj & 7) << 3))]) = wv;
    }
    // prefetch tile 1 raw q/y
    #pragma unroll
    for (int j = 0; j < 8; j++) {
        int gr = cr0 + BM + r0 + (j << 4);
        qv[j] = Q[(size_t)gr * 64 + n];
        yv[j] = Y[(size_t)gr * 64 + n];
    }
    __syncthreads();

    int cur = 0;
    for (int t = 0; t < NTILES; t++) {
        short* bufR = &sA[cur][0];
        short* bufW = &sA[cur ^ 1][0];

        // s for tile t+1 (staged this iteration)
        float sStage[8];
        #pragma unroll
        for (int j = 0; j < 8; j++) sStage[j] = qv[j] * yv[j];

        // prefetch raw q/y for tile t+2 (wraps harmlessly)
        #pragma unroll
        for (int j = 0; j < 8; j++) {
            int gr = cr0 + (((t + 2) & (NTILES - 1)) << 7) + r0 + (j << 4);
            qv[j] = Q[(size_t)gr * 64 + n];
            yv[j] = Y[(size_t)gr * 64 + n];
        }

        f32x4 acc[8][2] = {};

        #pragma unroll
        for (int ks = 0; ks < 8; ks++) {
            // A-frag reads for this k-slice (issued first: latency under VALU)
            bf16x8 afr[8];
            const int rpan = ks >> 1;
            const int rk   = ((ks & 1) << 5) + ((lane >> 4) << 3);
            #pragma unroll
            for (int m = 0; m < 8; m++) {
                int row = (m << 4) + (lane & 15);
                afr[m] = *reinterpret_cast<const bf16x8*>(
                    &bufR[rpan * PANEL + (((row << 6) + rk) ^ ((row & 7) << 3))]);
            }
            // stage row r0+16*ks of tile t+1 into write buffer
            {
                const float sv = sStage[ks];
                float h[8];
                #pragma unroll
                for (int i = 0; i < 8; i++)
                    h[i] = fmaxf(fmaf(sv, pw1[i], pb1[i]), 0.f);
                uint4 wv;
                wv.x = pack2bf(h[0], h[1]); wv.y = pack2bf(h[2], h[3]);
                wv.z = pack2bf(h[4], h[5]); wv.w = pack2bf(h[6], h[7]);
                int rj = r0 + (ks << 4);
                *reinterpret_cast<uint4*>(
                    &bufW[pan * PANEL + (((rj << 6) + k64) ^ ((rj & 7) << 3))]) = wv;
            }
            __builtin_amdgcn_s_setprio(1);
            #pragma unroll
            for (int m = 0; m < 8; m++)
                #pragma unroll
                for (int p = 0; p < 2; p++)
                    acc[m][p] = __builtin_amdgcn_mfma_f32_16x16x32_bf16(
                        afr[m], breg[p][ks], acc[m][p], 0, 0, 0);
            __builtin_amdgcn_s_setprio(0);
        }

        // ---- epilogue: z_part = sum_d relu(acc + b2) * w3, DPP row-reduce ----
        #pragma unroll
        for (int m = 0; m < 8; m++) {
            #pragma unroll
            for (int j = 0; j < 4; j++) {
                float pz = fmaxf(acc[m][0][j] + b2v[0], 0.f) * w3v[0]
                         + fmaxf(acc[m][1][j] + b2v[1], 0.f) * w3v[1];
                pz = row_reduce16(pz);
                if ((lane & 15) == 0)
                    zpart[cur][(m << 4) + ((lane >> 4) << 2) + j][wave] = pz;
            }
        }
        __syncthreads();
        if (tid < BM) {
            float z = b3n;
            #pragma unroll
            for (int w = 0; w < 8; w++) z += zpart[cur][tid][w];
            Zn[cr0 + (t << 7) + tid] = z;   // coalesced (node-major)
        }
        cur ^= 1;
    }
}

// ---------------------------------------------------------------------------
// Kernel 2: per-row 65-way softmax. One wave per batch row (lane = node).
// Z is node-major: Z[n][b].
// ---------------------------------------------------------------------------
__global__ __launch_bounds__(256) void softmax_rows(
    const float* __restrict__ Q, const float* __restrict__ Y,
    const float* __restrict__ Z, const float* __restrict__ bias0,
    float* __restrict__ out)
{
    const int lane = threadIdx.x & 63;
    const int wv   = threadIdx.x >> 6;
    const int b    = (blockIdx.x << 2) + wv;

    float s = Q[(size_t)b * 64 + lane] * Y[(size_t)b * 64 + lane];
    float ssum = s;
    #pragma unroll
    for (int mask = 32; mask >= 1; mask >>= 1) ssum += __shfl_xor(ssum, mask, 64);
    const float z0 = bias0[0] - ssum;

    float zl = Z[((size_t)lane << 13) + b];
    float mx = zl;
    #pragma unroll
    for (int mask = 32; mask >= 1; mask >>= 1) mx = fmaxf(mx, __shfl_xor(mx, mask, 64));
    mx = fmaxf(mx, z0);

    float el = expf(zl - mx);
    float e0 = expf(z0 - mx);
    float den = el;
    #pragma unroll
    for (int mask = 32; mask >= 1; mask >>= 1) den += __shfl_xor(den, mask, 64);
    den += e0;
    const float inv = 1.0f / den;

    out[(size_t)b * 65 + 1 + lane] = el * inv;
    if (lane == 0) out[(size_t)b * 65] = e0 * inv;
}

// ---------------------------------------------------------------------------
extern "C" void kernel_launch(void* const* d_in, const int* in_sizes, int n_in,
                              void* d_out, int out_size, void* d_ws, size_t ws_size,
                              hipStream_t stream)
{
    const float* Q     = (const float*)d_in[0];
    const float* Y     = (const float*)d_in[1];
    const float* W1    = (const float*)d_in[2];
    const float* b1    = (const float*)d_in[3];
    const float* W2    = (const float*)d_in[4];
    const float* b2    = (const float*)d_in[5];
    const float* W3    = (const float*)d_in[6];
    const float* b3    = (const float*)d_in[7];
    const float* bias0 = (const float*)d_in[8];
    float* out = (float*)d_out;

    // workspace: W2t bf16 (8.39 MB) | Z f32 logits, node-major [64][8192]
    unsigned short* W2t = (unsigned short*)d_ws;
    float* Z = (float*)((char*)d_ws + (size_t)64 * 256 * 256 * 2);

    transpose_w2<<<dim3(8, 8, 64), 256, 0, stream>>>(W2, W2t);
    gemm_node<<<dim3(4, 64), 512, 0, stream>>>(Q, Y, W1, b1, W2t, b2, W3, b3, Z);
    softmax_rows<<<2048, 256, 0, stream>>>(Q, Y, Z, bias0, out);
}

// Round 5
// 87.890 us; speedup vs baseline: 6.3846x; 1.1041x over previous
//
#include <hip/hip_runtime.h>
#include <hip/hip_bf16.h>

// B=8192 rows, N=64 nodes, C=256. Per node: MLP 1->C->C->1 on s=Q*Y,
// then softmax over [z0, z_1..z_64] per row. Output f32 [B, 65].
//
// Round 5: W2-resident GEMM, LDS-traffic-halved + VALU-slimmed.
//  - 8 waves as 2x4: wave owns 64 rows x 64 cols -> A-reads halve (32/tile)
//  - breg[4][8]=128 VGPR + acc[4][4]=64: ~245 unified, 2 waves/SIMD
//  - v_cvt_pk_bf16_f32 asm for H1 bf16 pack (1 inst/pair)
//  - s = Q*Y precomputed node-major (make_s), block loads coalesced -> s_lds
//  - swizzle decomposed to lane-base + immediate offsets (addr VALU ~0)

#define BM 128
#define CHUNK 2048
#define NTILES 16
#define PANEL 8200   // (128*64 + 8) shorts per K-panel (conflict-free, measured R3/R4)

typedef __attribute__((ext_vector_type(8))) short bf16x8;
typedef __attribute__((ext_vector_type(4))) float f32x4;

__device__ __forceinline__ unsigned short f2bf(float f) {
    unsigned int u = __float_as_uint(f);
    u += 0x7FFFu + ((u >> 16) & 1u);   // RNE
    return (unsigned short)(u >> 16);
}

// dst.lo = bf16(a), dst.hi = bf16(b) — single HW instruction
__device__ __forceinline__ unsigned int cvtpk(float a, float b) {
    unsigned int r;
    asm("v_cvt_pk_bf16_f32 %0, %1, %2" : "=v"(r) : "v"(a), "v"(b));
    return r;
}

// sum across the 16 lanes of each DPP row
__device__ __forceinline__ float row_reduce16(float x) {
    int v;
    v = __builtin_amdgcn_update_dpp(0, __float_as_int(x), 0xB1, 0xF, 0xF, false);  // quad_perm [1,0,3,2]
    x += __int_as_float(v);
    v = __builtin_amdgcn_update_dpp(0, __float_as_int(x), 0x4E, 0xF, 0xF, false);  // quad_perm [2,3,0,1]
    x += __int_as_float(v);
    v = __builtin_amdgcn_update_dpp(0, __float_as_int(x), 0x124, 0xF, 0xF, false); // row_ror:4
    x += __int_as_float(v);
    v = __builtin_amdgcn_update_dpp(0, __float_as_int(x), 0x128, 0xF, 0xF, false); // row_ror:8
    x += __int_as_float(v);
    return x;
}

// ---------------------------------------------------------------------------
// Kernel 0: W2 [N][C][D] f32 -> W2t [N][D][C] bf16 (K-contiguous for MFMA B).
// ---------------------------------------------------------------------------
__global__ __launch_bounds__(256) void transpose_w2(
    const float* __restrict__ W2, unsigned short* __restrict__ W2t)
{
    __shared__ float tile[32][33];
    const int n  = blockIdx.z;
    const int c0 = blockIdx.y << 5;
    const int d0 = blockIdx.x << 5;
    const int tx = threadIdx.x & 31;
    const int ty = threadIdx.x >> 5;
    const float* src = W2 + ((size_t)n << 16);
    #pragma unroll
    for (int j = 0; j < 32; j += 8)
        tile[ty + j][tx] = src[(size_t)(c0 + ty + j) * 256 + d0 + tx];
    __syncthreads();
    unsigned short* dst = W2t + ((size_t)n << 16);
    #pragma unroll
    for (int j = 0; j < 32; j += 8)
        dst[(size_t)(d0 + ty + j) * 256 + c0 + tx] = f2bf(tile[tx][ty + j]);
}

// ---------------------------------------------------------------------------
// Kernel 0b: S[n][b] = Q[b][n]*Y[b][n]  (node-major, 64x64 LDS transpose)
// ---------------------------------------------------------------------------
__global__ __launch_bounds__(256) void make_s(
    const float* __restrict__ Q, const float* __restrict__ Y,
    float* __restrict__ S)
{
    __shared__ float ts[64][65];
    const int b0 = blockIdx.x << 6;
    #pragma unroll
    for (int jj = 0; jj < 16; jj++) {
        int idx = threadIdx.x + (jj << 8);
        int r = idx >> 6, c = idx & 63;
        ts[r][c] = Q[(size_t)(b0 + r) * 64 + c] * Y[(size_t)(b0 + r) * 64 + c];
    }
    __syncthreads();
    #pragma unroll
    for (int jj = 0; jj < 16; jj++) {
        int idx = threadIdx.x + (jj << 8);
        int nn = idx >> 6, bb = idx & 63;
        S[((size_t)nn << 13) + b0 + bb] = ts[bb][nn];
    }
}

// ---------------------------------------------------------------------------
// Kernel 1: W2-resident fused MLP GEMM. grid (64 nodes, 4 chunks), 512 thr.
// Wave (wr,wc) in 2x4: 64 rows x 64 cols. breg[4][8], acc[4][4].
// ---------------------------------------------------------------------------
__global__ __launch_bounds__(512, 1) void gemm_node(
    const float* __restrict__ S,
    const float* __restrict__ W1, const float* __restrict__ b1,
    const unsigned short* __restrict__ W2t,
    const float* __restrict__ b2, const float* __restrict__ W3,
    const float* __restrict__ b3, float* __restrict__ Z)
{
    __shared__ short sA[2][4 * PANEL];    // 131,200 B, double-buffered A
    __shared__ float zpart[2][4][BM];     // 4,096 B  (wc-major)
    __shared__ float s_lds[CHUNK];        // 8,192 B

    const int tid  = threadIdx.x;
    const int lane = tid & 63;
    const int wave = tid >> 6;
    const int wr   = wave >> 2;           // 0..1 : row half (64 rows)
    const int wc   = wave & 3;            // 0..3 : col quarter (64 cols)
    const int n    = blockIdx.x;
    const int cr0  = blockIdx.y * CHUNK;

    // staging: fixed 8-short k-window, rows r0 + 16*ks
    const int r0  = tid >> 5;             // 0..15
    const int kc  = (tid & 31) << 3;      // 0..248
    const int stBase = (kc >> 6) * PANEL + (r0 << 6) + ((kc & 63) ^ ((r0 & 7) << 3));

    // A-read lane base (swizzle folded; per-(m,ks) parts are immediates)
    const int aE = (wr << 12) + ((lane & 15) << 6)
                 + ((((lane >> 4) << 3)) ^ ((lane & 3) << 3))
                 + ((lane & 4) << 3);
    const int aO = aE ^ 32;

    const float* W1n = W1 + n * 256;
    const float* b1n = b1 + n * 256;
    const unsigned short* W2n = W2t + ((size_t)n << 16);
    const float* Sn = S + ((size_t)n << 13);
    float* Zn = Z + ((size_t)n << 13);

    // ---- fill s_lds: one coalesced float4 per thread ----
    {
        float4 v = *reinterpret_cast<const float4*>(Sn + cr0 + (tid << 2));
        *reinterpret_cast<float4*>(&s_lds[tid << 2]) = v;
    }

    // ---- hoisted per-thread W1/b1 window (16 regs) ----
    float pw1[8], pb1[8];
    {
        float4 wa = *reinterpret_cast<const float4*>(&W1n[kc]);
        float4 wb = *reinterpret_cast<const float4*>(&W1n[kc + 4]);
        float4 ba = *reinterpret_cast<const float4*>(&b1n[kc]);
        float4 bb = *reinterpret_cast<const float4*>(&b1n[kc + 4]);
        pw1[0]=wa.x; pw1[1]=wa.y; pw1[2]=wa.z; pw1[3]=wa.w;
        pw1[4]=wb.x; pw1[5]=wb.y; pw1[6]=wb.z; pw1[7]=wb.w;
        pb1[0]=ba.x; pb1[1]=ba.y; pb1[2]=ba.z; pb1[3]=ba.w;
        pb1[4]=bb.x; pb1[5]=bb.y; pb1[6]=bb.z; pb1[7]=bb.w;
    }

    // ---- B fragments: wave's 64-col slice of W2[n] in regs (128 VGPR) ----
    bf16x8 breg[4][8];
    #pragma unroll
    for (int p = 0; p < 4; p++)
        #pragma unroll
        for (int ks = 0; ks < 8; ks++) {
            int col = (wc << 6) + (p << 4) + (lane & 15);
            int k   = (ks << 5) + ((lane >> 4) << 3);
            breg[p][ks] = *reinterpret_cast<const bf16x8*>(&W2n[(size_t)col * 256 + k]);
        }

    // ---- hoisted epilogue constants ----
    float w3v[4], b2v[4];
    #pragma unroll
    for (int p = 0; p < 4; p++) {
        int d = (wc << 6) + (p << 4) + (lane & 15);
        w3v[p] = W3[n * 256 + d];
        b2v[p] = b2[n * 256 + d];
    }
    const float b3n = b3[n];

    __syncthreads();   // s_lds ready

    // ---- prologue: stage tile 0 into buf 0 ----
    {
        short* bW = (short*)sA[0] + stBase;
        const float* sp = &s_lds[r0];
        #pragma unroll
        for (int ks = 0; ks < 8; ks++) {
            const float sv = sp[ks << 4];
            float h[8];
            #pragma unroll
            for (int i = 0; i < 8; i++)
                h[i] = fmaxf(fmaf(sv, pw1[i], pb1[i]), 0.f);
            uint4 wv;
            wv.x = cvtpk(h[0], h[1]); wv.y = cvtpk(h[2], h[3]);
            wv.z = cvtpk(h[4], h[5]); wv.w = cvtpk(h[6], h[7]);
            *reinterpret_cast<uint4*>(bW + (ks << 10)) = wv;
        }
    }
    __syncthreads();   // tile 0 staged

    int cur = 0;
    for (int t = 0; t < NTILES; t++) {
        const short* bR = sA[cur];
        short* bW = (short*)sA[cur ^ 1] + stBase;
        const float* sp = &s_lds[(((t + 1) & 15) << 7) + r0];

        f32x4 acc[4][4] = {};

        #pragma unroll
        for (int ks = 0; ks < 8; ks++) {
            // A-frag reads (immediate offsets off one lane base)
            bf16x8 afr[4];
            {
                const short* ab = bR + ((ks & 1) ? aO : aE) + (ks >> 1) * PANEL;
                #pragma unroll
                for (int m = 0; m < 4; m++)
                    afr[m] = *reinterpret_cast<const bf16x8*>(ab + (m << 10));
            }
            // stage row r0+16*ks of tile t+1
            {
                const float sv = sp[ks << 4];
                float h[8];
                #pragma unroll
                for (int i = 0; i < 8; i++)
                    h[i] = fmaxf(fmaf(sv, pw1[i], pb1[i]), 0.f);
                uint4 wv;
                wv.x = cvtpk(h[0], h[1]); wv.y = cvtpk(h[2], h[3]);
                wv.z = cvtpk(h[4], h[5]); wv.w = cvtpk(h[6], h[7]);
                *reinterpret_cast<uint4*>(bW + (ks << 10)) = wv;
            }
            __builtin_amdgcn_s_setprio(1);
            #pragma unroll
            for (int m = 0; m < 4; m++)
                #pragma unroll
                for (int p = 0; p < 4; p++)
                    acc[m][p] = __builtin_amdgcn_mfma_f32_16x16x32_bf16(
                        afr[m], breg[p][ks], acc[m][p], 0, 0, 0);
            __builtin_amdgcn_s_setprio(0);
        }

        // ---- epilogue: pz = sum_d relu(acc + b2) * w3, DPP 16-lane reduce ----
        #pragma unroll
        for (int m = 0; m < 4; m++) {
            f32x4 pzv = {0.f, 0.f, 0.f, 0.f};
            #pragma unroll
            for (int p = 0; p < 4; p++)
                #pragma unroll
                for (int j = 0; j < 4; j++)
                    pzv[j] = fmaf(fmaxf(acc[m][p][j] + b2v[p], 0.f), w3v[p], pzv[j]);
            #pragma unroll
            for (int j = 0; j < 4; j++) pzv[j] = row_reduce16(pzv[j]);
            if ((lane & 15) == 0)
                *reinterpret_cast<f32x4*>(
                    &zpart[cur][wc][(wr << 6) + (m << 4) + ((lane >> 4) << 2)]) = pzv;
        }
        __syncthreads();
        if (tid < BM) {
            float z = zpart[cur][0][tid] + zpart[cur][1][tid]
                    + zpart[cur][2][tid] + zpart[cur][3][tid] + b3n;
            Zn[cr0 + (t << 7) + tid] = z;   // coalesced (node-major)
        }
        cur ^= 1;
    }
}

// ---------------------------------------------------------------------------
// Kernel 2: per-row 65-way softmax. One wave per batch row (lane = node).
// Z node-major: Z[n][b].
// ---------------------------------------------------------------------------
__global__ __launch_bounds__(256) void softmax_rows(
    const float* __restrict__ Q, const float* __restrict__ Y,
    const float* __restrict__ Z, const float* __restrict__ bias0,
    float* __restrict__ out)
{
    const int lane = threadIdx.x & 63;
    const int wv   = threadIdx.x >> 6;
    const int b    = (blockIdx.x << 2) + wv;

    float s = Q[(size_t)b * 64 + lane] * Y[(size_t)b * 64 + lane];
    float ssum = s;
    #pragma unroll
    for (int mask = 32; mask >= 1; mask >>= 1) ssum += __shfl_xor(ssum, mask, 64);
    const float z0 = bias0[0] - ssum;

    float zl = Z[((size_t)lane << 13) + b];
    float mx = zl;
    #pragma unroll
    for (int mask = 32; mask >= 1; mask >>= 1) mx = fmaxf(mx, __shfl_xor(mx, mask, 64));
    mx = fmaxf(mx, z0);

    float el = expf(zl - mx);
    float e0 = expf(z0 - mx);
    float den = el;
    #pragma unroll
    for (int mask = 32; mask >= 1; mask >>= 1) den += __shfl_xor(den, mask, 64);
    den += e0;
    const float inv = 1.0f / den;

    out[(size_t)b * 65 + 1 + lane] = el * inv;
    if (lane == 0) out[(size_t)b * 65] = e0 * inv;
}

// ---------------------------------------------------------------------------
extern "C" void kernel_launch(void* const* d_in, const int* in_sizes, int n_in,
                              void* d_out, int out_size, void* d_ws, size_t ws_size,
                              hipStream_t stream)
{
    const float* Q     = (const float*)d_in[0];
    const float* Y     = (const float*)d_in[1];
    const float* W1    = (const float*)d_in[2];
    const float* b1    = (const float*)d_in[3];
    const float* W2    = (const float*)d_in[4];
    const float* b2    = (const float*)d_in[5];
    const float* W3    = (const float*)d_in[6];
    const float* b3    = (const float*)d_in[7];
    const float* bias0 = (const float*)d_in[8];
    float* out = (float*)d_out;

    // ws: W2t bf16 8.39MB | Z f32 node-major 2.10MB | S f32 node-major 2.10MB
    unsigned short* W2t = (unsigned short*)d_ws;
    float* Z = (float*)((char*)d_ws + (size_t)8388608);
    float* S = (float*)((char*)d_ws + (size_t)8388608 + 2097152);

    transpose_w2<<<dim3(8, 8, 64), 256, 0, stream>>>(W2, W2t);
    make_s<<<128, 256, 0, stream>>>(Q, Y, S);
    gemm_node<<<dim3(64, 4), 512, 0, stream>>>(S, W1, b1, W2t, b2, W3, b3, Z);
    softmax_rows<<<2048, 256, 0, stream>>>(Q, Y, Z, bias0, out);
}